// Round 5
// baseline (68.569 us; speedup 1.0000x reference)
//
#include <hip/hip_runtime.h>
#include <math.h>

#define NS 1024
#define NU 32
#define ND 256
#define NROWS (NS * NU)             // 32768
#define BM 256                      // rows per k2 block
#define BN 512                      // cols per k2 block
#define NBLK ((NROWS / BM) * (NS / BN))   // 128 * 2 = 256 blocks

static constexpr float EPS_POS = 1e-6f;
static constexpr float EPS_NEG = 1e-8f;

typedef __attribute__((ext_vector_type(8))) short bf16x8;
typedef __attribute__((ext_vector_type(4))) float f32x4;

#if __has_builtin(__builtin_amdgcn_exp2f)
#define EXP2F(x) __builtin_amdgcn_exp2f(x)
#else
#define EXP2F(x) exp2f(x)
#endif

static __device__ __forceinline__ unsigned short f2bf(float f) {
    union { float f; unsigned u; } v; v.f = f;
    unsigned r = v.u + 0x7fffu + ((v.u >> 16) & 1u);   // RNE
    return (unsigned short)(r >> 16);
}

// ---------------------------------------------------------------------------
// Kernel 1: per-speaker centroids (-> bf16 normalized, row-major cnb[t][d]),
// positive (LOO) cosines, inverse row norms. One block per speaker.
// ---------------------------------------------------------------------------
__global__ __launch_bounds__(256) void ge2e_k1(
    const float* __restrict__ dv, unsigned short* __restrict__ cnb,
    float* __restrict__ invn, float* __restrict__ blk_pos)
{
    const int s = blockIdx.x;
    const int tid = threadIdx.x;
    const int wave = tid >> 6;
    const int lane = tid & 63;

    __shared__ float v[NU][ND];
    __shared__ float cs[ND];
    __shared__ float red[16];

    const float* base = dv + (size_t)s * (NU * ND);
    for (int idx = tid; idx < NU * ND; idx += 256) {
        v[idx >> 8][idx & 255] = base[idx];
    }
    __syncthreads();

    {
        float a = 0.f;
        #pragma unroll
        for (int u = 0; u < NU; ++u) a += v[u][tid];
        cs[tid] = a;
    }
    __syncthreads();

    // centroid norm -> normalized centroid in bf16, row-major [t][d]
    float c = cs[tid] * (1.0f / NU);
    float p = c * c;
    #pragma unroll
    for (int off = 32; off > 0; off >>= 1) p += __shfl_xor(p, off, 64);
    if (lane == 0) red[wave] = p;
    __syncthreads();
    if (tid == 0) red[8] = red[0] + red[1] + red[2] + red[3];
    __syncthreads();
    {
        float rn = 1.0f / fmaxf(sqrtf(red[8]), EPS_NEG);
        cnb[(size_t)s * ND + tid] = f2bf(c * rn);
    }

    // per-utterance stats: wave w handles u = 8w .. 8w+7
    const float inv31 = 1.0f / (NU - 1);
    float pos_part = 0.f;
    const float4 cc = *(const float4*)&cs[lane * 4];
    for (int uu = 0; uu < 8; ++uu) {
        const int u = wave * 8 + uu;
        const float4 vv = *(const float4*)&v[u][lane * 4];
        float pv = 0.f, pp = 0.f, px = 0.f;
        float pc;
        pc = (cc.x - vv.x) * inv31; pv += vv.x * vv.x; pp += pc * pc; px += vv.x * pc;
        pc = (cc.y - vv.y) * inv31; pv += vv.y * vv.y; pp += pc * pc; px += vv.y * pc;
        pc = (cc.z - vv.z) * inv31; pv += vv.z * vv.z; pp += pc * pc; px += vv.z * pc;
        pc = (cc.w - vv.w) * inv31; pv += vv.w * vv.w; pp += pc * pc; px += vv.w * pc;
        #pragma unroll
        for (int off = 32; off > 0; off >>= 1) {
            pv += __shfl_xor(pv, off, 64);
            pp += __shfl_xor(pp, off, 64);
            px += __shfl_xor(px, off, 64);
        }
        if (lane == 0) {
            float nv = sqrtf(pv), npc = sqrtf(pp);
            pos_part += px / (fmaxf(nv, EPS_POS) * fmaxf(npc, EPS_POS));
            invn[s * NU + u] = 1.0f / fmaxf(nv, EPS_NEG);
        }
    }
    if (lane == 0) red[4 + wave] = pos_part;
    __syncthreads();
    if (tid == 0) blk_pos[s] = red[4] + red[5] + red[6] + red[7];
}

// ---------------------------------------------------------------------------
// Kernel 2: register-resident-A MFMA GEMM (BM=256 rows x BN=512 cols, K=256)
// with fused fixed-reference sum-exp epilogue. 256 blocks x 512 threads
// (8 waves = 4 mg x 2 ng). Writes PER-ROW partial sum-of-exp to rowse
// (no logs here — lse needs the cross-block sum first; R4's bug).
// ---------------------------------------------------------------------------
__global__ __launch_bounds__(512, 2) void ge2e_k2(
    const float* __restrict__ dv, const unsigned short* __restrict__ cnb,
    const float* __restrict__ invn, const float* __restrict__ wp,
    const float* __restrict__ bp, float* __restrict__ rowse,
    float* __restrict__ blk_neg)
{
    const int blk = blockIdx.x;
    const int bm = blk >> 1;
    const int bn = blk & 1;
    const int r0 = bm * BM;
    const int tid = threadIdx.x;
    const int w  = tid >> 6;
    const int l  = tid & 63;
    const int lr = l & 15;
    const int lg = l >> 4;
    const int mg = w & 3;    // rows mg*64 .. +64
    const int ng = w >> 2;   // cols bn*512 + ng*256 .. +256
    const int rsw = lr & 7;

    __shared__ unsigned short Bst[2][32][256];   // 32 KB double buffer
    __shared__ float pse[2][BM];
    __shared__ float psm[2][BM];
    __shared__ float redn[8];

    const float w0 = wp[0];
    const float c2 = w0 * 1.4426950408889634f;   // w0 * log2(e)

    // --- B stage addressing: per-lane pre-swizzled global source, linear LDS
    size_t srcb[2];
    unsigned ldso[2];
    #pragma unroll
    for (int i = 0; i < 2; ++i) {
        const int gi = w * 128 + i * 64 + l;     // granule 0..1023 of the step
        const int rr = gi >> 5;                  // staged col row 0..31
        const int gc = gi & 31;                  // granule within 512B row
        const int t0 = bn * 512 + (rr >> 4) * 256 + (rr & 15);
        srcb[i] = (size_t)t0 * 512 + (size_t)(gc ^ (rr & 7)) * 16;
        ldso[i] = (unsigned)(w * 128 + i * 64) * 16;   // wave-uniform base
    }
    const char* cnbc = (const char*)cnb;

    // issue B stage 0
    #pragma unroll
    for (int i = 0; i < 2; ++i) {
        __builtin_amdgcn_global_load_lds(
            (const __attribute__((address_space(1))) void*)(cnbc + srcb[i]),
            (__attribute__((address_space(3))) void*)((char*)&Bst[0][0][0] + ldso[i]),
            16, 0, 0);
    }

    // --- A fragments: global fp32 -> registers (bf16), 64 rows per wave
    bf16x8 afr[4][8];
    #pragma unroll
    for (int mt = 0; mt < 4; ++mt) {
        const int grow = r0 + mg * 64 + mt * 16 + lr;
        const float sc = invn[grow];
        const float* rbase = dv + (size_t)grow * ND;
        #pragma unroll
        for (int kt = 0; kt < 8; ++kt) {
            const float4 x = *(const float4*)(rbase + kt * 32 + lg * 8);
            const float4 y = *(const float4*)(rbase + kt * 32 + lg * 8 + 4);
            uint4 pk;
            pk.x = (unsigned)f2bf(x.x * sc) | ((unsigned)f2bf(x.y * sc) << 16);
            pk.y = (unsigned)f2bf(x.z * sc) | ((unsigned)f2bf(x.w * sc) << 16);
            pk.z = (unsigned)f2bf(y.x * sc) | ((unsigned)f2bf(y.y * sc) << 16);
            pk.w = (unsigned)f2bf(y.z * sc) | ((unsigned)f2bf(y.w * sc) << 16);
            afr[mt][kt] = *(bf16x8*)&pk;
        }
    }

    float se[4][4], sm[4][4];
    #pragma unroll
    for (int mt = 0; mt < 4; ++mt)
        #pragma unroll
        for (int r = 0; r < 4; ++r) { se[mt][r] = 0.f; sm[mt][r] = 0.f; }

    // own-speaker column bookkeeping (per mt; wave-uniform except lr)
    int town[4];
    #pragma unroll
    for (int mt = 0; mt < 4; ++mt) town[mt] = (r0 + mg * 64 + mt * 16) >> 5;

    for (int j = 0; j < 16; ++j) {
        __syncthreads();   // stage j landed; all waves done reading buf j^1

        if (j < 15) {      // issue stage j+1 into the other buffer
            char* bdst = (char*)&Bst[(j + 1) & 1][0][0];
            const size_t soff = (size_t)(j + 1) * 8192;
            #pragma unroll
            for (int i = 0; i < 2; ++i) {
                __builtin_amdgcn_global_load_lds(
                    (const __attribute__((address_space(1))) void*)(cnbc + srcb[i] + soff),
                    (__attribute__((address_space(3))) void*)(bdst + ldso[i]),
                    16, 0, 0);
            }
        }

        const unsigned short (*bc)[256] = Bst[j & 1];
        f32x4 acc[4];
        #pragma unroll
        for (int mt = 0; mt < 4; ++mt) acc[mt] = (f32x4){0.f, 0.f, 0.f, 0.f};

        #pragma unroll
        for (int kt = 0; kt < 8; ++kt) {
            const bf16x8 bfr = *(const bf16x8*)&bc[ng * 16 + lr][(((kt * 4 + lg)) ^ rsw) * 8];
            #pragma unroll
            for (int mt = 0; mt < 4; ++mt)
                acc[mt] = __builtin_amdgcn_mfma_f32_16x16x32_bf16(afr[mt][kt], bfr, acc[mt], 0, 0, 0);
        }

        // branchless fixed-reference fold (cos <= 1 => reference M = 1)
        #pragma unroll
        for (int mt = 0; mt < 4; ++mt)
            #pragma unroll
            for (int r = 0; r < 4; ++r) {
                const float cv = acc[mt][r];
                se[mt][r] += EXP2F(fmaf(c2, cv, -c2));
                sm[mt][r] += cv;
            }

        // own-speaker column subtract (wave-uniform step/ng/bn tests)
        #pragma unroll
        for (int mt = 0; mt < 4; ++mt) {
            const int tn = town[mt];
            if ((tn >> 9) == bn && ((tn >> 8) & 1) == ng && ((tn >> 4) & 15) == j) {
                if (lr == (tn & 15)) {
                    #pragma unroll
                    for (int r = 0; r < 4; ++r) {
                        const float cv = acc[mt][r];
                        se[mt][r] -= EXP2F(fmaf(c2, cv, -c2));
                        sm[mt][r] -= cv;
                    }
                }
            }
        }
    }

    // reduce across the 16 column-lanes (xor bits 0..3)
    #pragma unroll
    for (int mask = 1; mask <= 8; mask <<= 1)
        #pragma unroll
        for (int mt = 0; mt < 4; ++mt)
            #pragma unroll
            for (int r = 0; r < 4; ++r) {
                se[mt][r] += __shfl_xor(se[mt][r], mask, 64);
                sm[mt][r] += __shfl_xor(sm[mt][r], mask, 64);
            }

    if (lr == 0) {
        #pragma unroll
        for (int mt = 0; mt < 4; ++mt)
            #pragma unroll
            for (int r = 0; r < 4; ++r) {
                const int row = mg * 64 + mt * 16 + lg * 4 + r;
                pse[ng][row] = se[mt][r];
                psm[ng][row] = sm[mt][r];
            }
    }
    __syncthreads();

    if (tid < BM) {
        // per-row partial sum over this block's 512 columns -> global
        rowse[(size_t)bn * NROWS + r0 + tid] = pse[0][tid] + pse[1][tid];
        float smt = psm[0][tid] + psm[1][tid];
        #pragma unroll
        for (int mask = 1; mask <= 32; mask <<= 1)
            smt += __shfl_xor(smt, mask, 64);
        if ((tid & 63) == 0) redn[tid >> 6] = smt;
    }
    __syncthreads();
    if (tid == 0) blk_neg[blk] = redn[0] + redn[1] + redn[2] + redn[3];
}

// ---------------------------------------------------------------------------
// Kernel 3: per-row lse over combined column halves + final reduction
// -> (loss, pos_mean, neg_mean). One block x 1024 threads.
// ---------------------------------------------------------------------------
__global__ __launch_bounds__(1024) void ge2e_k3(
    const float* __restrict__ blk_pos, const float* __restrict__ blk_neg,
    const float* __restrict__ rowse, const float* __restrict__ wp,
    const float* __restrict__ bp, float* __restrict__ out)
{
    const int tid = threadIdx.x;
    __shared__ float red[48];

    float p = 0.f, n = 0.f, l = 0.f;
    if (tid < NS) p = blk_pos[tid];
    if (tid < NBLK) n = blk_neg[tid];
    for (int r = tid; r < NROWS; r += 1024)
        l += __logf(rowse[r] + rowse[NROWS + r]);

    #pragma unroll
    for (int off = 32; off > 0; off >>= 1) {
        p += __shfl_xor(p, off, 64);
        n += __shfl_xor(n, off, 64);
        l += __shfl_xor(l, off, 64);
    }
    const int wave = tid >> 6, lane = tid & 63;
    if (lane == 0) { red[wave] = p; red[16 + wave] = n; red[32 + wave] = l; }
    __syncthreads();
    if (tid == 0) {
        float ps = 0.f, ns = 0.f, ls = 0.f;
        #pragma unroll
        for (int q = 0; q < 16; ++q) {
            ps += red[q]; ns += red[16 + q]; ls += red[32 + q];
        }
        const float w0 = wp[0];
        const float b0 = bp[0];
        const float pos_mean = ps * (1.0f / NROWS);
        const float neg_mean = ns / ((float)NS * (float)NU * (float)(NS - 1));
        // lse_r = w0 + b0 + log(st_r); mean over rows
        const float lse_mean = w0 + b0 + ls * (1.0f / NROWS);
        const float loss = -(w0 * pos_mean + b0) + lse_mean;
        out[0] = loss;
        out[1] = pos_mean;
        out[2] = neg_mean;
    }
}

extern "C" void kernel_launch(void* const* d_in, const int* in_sizes, int n_in,
                              void* d_out, int out_size, void* d_ws, size_t ws_size,
                              hipStream_t stream)
{
    const float* dv = (const float*)d_in[0];
    const float* w  = (const float*)d_in[1];
    const float* b  = (const float*)d_in[2];
    float* out = (float*)d_out;

    unsigned short* cnb = (unsigned short*)d_ws;           // [NS][ND] bf16, 512 KB
    float* invn    = (float*)(cnb + (size_t)NS * ND);      // [NROWS]
    float* blk_pos = invn + NROWS;                         // [NS]
    float* blk_neg = blk_pos + NS;                         // [NBLK]
    float* rowse   = blk_neg + NBLK;                       // [2 * NROWS]

    hipLaunchKernelGGL(ge2e_k1, dim3(NS), dim3(256), 0, stream,
                       dv, cnb, invn, blk_pos);
    hipLaunchKernelGGL(ge2e_k2, dim3(NBLK), dim3(512), 0, stream,
                       dv, cnb, invn, w, b, rowse, blk_neg);
    hipLaunchKernelGGL(ge2e_k3, dim3(1), dim3(1024), 0, stream,
                       blk_pos, blk_neg, rowse, w, b, out);
}

// Round 6
// 53.338 us; speedup vs baseline: 1.2855x; 1.2855x over previous
//
#include <hip/hip_runtime.h>
#include <math.h>

#define NS 1024
#define NU 32
#define ND 256
#define NROWS (NS * NU)             // 32768
#define BM 128                      // rows per k2 block
#define NBLK (NROWS / BM)           // 256 blocks, full 1024 cols each

static constexpr float EPS_POS = 1e-6f;
static constexpr float EPS_NEG = 1e-8f;

typedef __attribute__((ext_vector_type(8))) short bf16x8;
typedef __attribute__((ext_vector_type(4))) float f32x4;

#if __has_builtin(__builtin_amdgcn_exp2f)
#define EXP2F(x) __builtin_amdgcn_exp2f(x)
#else
#define EXP2F(x) exp2f(x)
#endif

static __device__ __forceinline__ unsigned short f2bf(float f) {
    union { float f; unsigned u; } v; v.f = f;
    unsigned r = v.u + 0x7fffu + ((v.u >> 16) & 1u);   // RNE
    return (unsigned short)(r >> 16);
}

// ---------------------------------------------------------------------------
// Kernel 1: per-speaker centroids (-> bf16 normalized, row-major cnb[t][d]),
// positive (LOO) cosines, inverse row norms. One block per speaker.
// ---------------------------------------------------------------------------
__global__ __launch_bounds__(256) void ge2e_k1(
    const float* __restrict__ dv, unsigned short* __restrict__ cnb,
    float* __restrict__ invn, float* __restrict__ blk_pos)
{
    const int s = blockIdx.x;
    const int tid = threadIdx.x;
    const int wave = tid >> 6;
    const int lane = tid & 63;

    __shared__ float v[NU][ND];
    __shared__ float cs[ND];
    __shared__ float red[16];

    const float* base = dv + (size_t)s * (NU * ND);
    for (int idx = tid; idx < NU * ND; idx += 256) {
        v[idx >> 8][idx & 255] = base[idx];
    }
    __syncthreads();

    {
        float a = 0.f;
        #pragma unroll
        for (int u = 0; u < NU; ++u) a += v[u][tid];
        cs[tid] = a;
    }
    __syncthreads();

    // centroid norm -> normalized centroid in bf16, row-major [t][d]
    float c = cs[tid] * (1.0f / NU);
    float p = c * c;
    #pragma unroll
    for (int off = 32; off > 0; off >>= 1) p += __shfl_xor(p, off, 64);
    if (lane == 0) red[wave] = p;
    __syncthreads();
    if (tid == 0) red[8] = red[0] + red[1] + red[2] + red[3];
    __syncthreads();
    {
        float rn = 1.0f / fmaxf(sqrtf(red[8]), EPS_NEG);
        cnb[(size_t)s * ND + tid] = f2bf(c * rn);
    }

    // per-utterance stats: wave w handles u = 8w .. 8w+7
    const float inv31 = 1.0f / (NU - 1);
    float pos_part = 0.f;
    const float4 cc = *(const float4*)&cs[lane * 4];
    for (int uu = 0; uu < 8; ++uu) {
        const int u = wave * 8 + uu;
        const float4 vv = *(const float4*)&v[u][lane * 4];
        float pv = 0.f, pp = 0.f, px = 0.f;
        float pc;
        pc = (cc.x - vv.x) * inv31; pv += vv.x * vv.x; pp += pc * pc; px += vv.x * pc;
        pc = (cc.y - vv.y) * inv31; pv += vv.y * vv.y; pp += pc * pc; px += vv.y * pc;
        pc = (cc.z - vv.z) * inv31; pv += vv.z * vv.z; pp += pc * pc; px += vv.z * pc;
        pc = (cc.w - vv.w) * inv31; pv += vv.w * vv.w; pp += pc * pc; px += vv.w * pc;
        #pragma unroll
        for (int off = 32; off > 0; off >>= 1) {
            pv += __shfl_xor(pv, off, 64);
            pp += __shfl_xor(pp, off, 64);
            px += __shfl_xor(px, off, 64);
        }
        if (lane == 0) {
            float nv = sqrtf(pv), npc = sqrtf(pp);
            pos_part += px / (fmaxf(nv, EPS_POS) * fmaxf(npc, EPS_POS));
            invn[s * NU + u] = 1.0f / fmaxf(nv, EPS_NEG);
        }
    }
    if (lane == 0) red[4 + wave] = pos_part;
    __syncthreads();
    if (tid == 0) blk_pos[s] = red[4] + red[5] + red[6] + red[7];
}

// ---------------------------------------------------------------------------
// Kernel 2: MFMA GEMM, BM=128 rows x ALL 1024 cols, K=256. 256 blocks x 512
// threads (8 waves = 2 mg x 4 ng). A: staged coalesced to padded LDS, then
// frag-loaded to registers and PINNED via asm (compiler cannot sink/remat —
// R5's VGPR=108 pathology). B: 64-col slabs (32 KB) double-buffered via
// global_load_lds w=16, involutive granule swizzle on source+read (rule 21).
// Full row lives in one block -> lse finished here (no cross-block log bug).
// ---------------------------------------------------------------------------
__global__ __launch_bounds__(512, 2) void ge2e_k2(
    const float* __restrict__ dv, const unsigned short* __restrict__ cnb,
    const float* __restrict__ invn, const float* __restrict__ wp,
    const float* __restrict__ bp, float* __restrict__ blk_neg,
    float* __restrict__ blk_lse)
{
    const int blk = blockIdx.x;
    const int r0 = blk * BM;
    const int tid = threadIdx.x;
    const int w  = tid >> 6;
    const int l  = tid & 63;
    const int lr = l & 15;
    const int lg = l >> 4;
    const int mg = w >> 2;   // 0..1: rows mg*64 .. +64
    const int ng = w & 3;    // 0..3: cols j*64 + ng*16 .. +16
    const int rsw = lr & 7;

    __shared__ unsigned short Al[BM][264];        // 67.6 KB padded A tile
    __shared__ unsigned short Bst[2][64][256];    // 64 KB double buffer
    __shared__ float sinv[BM];
    __shared__ float pse[4][BM];
    __shared__ float psm[4][BM];
    __shared__ float redn[2], redl[2];

    const float w0 = wp[0];
    const float b0 = bp[0];
    const float c2 = w0 * 1.4426950408889634f;    // w0 * log2(e)

    if (tid < BM) sinv[tid] = invn[r0 + tid];

    // --- B stage addressing: per-lane pre-swizzled global src, linear LDS
    unsigned srcb[4], ldso[4];
    #pragma unroll
    for (int i = 0; i < 4; ++i) {
        const int gi = w * 256 + i * 64 + l;   // granule 0..2047 of the slab
        const int rr = gi >> 5;                // slab col 0..63
        const int gc = gi & 31;                // 16B granule within 512B col
        srcb[i] = (unsigned)(rr * 512 + (gc ^ (rr & 7)) * 16);
        ldso[i] = (unsigned)(w * 256 + i * 64) * 16;   // wave-uniform
    }
    const char* cnbc = (const char*)cnb;

    // issue B stage 0 (slab j=0)
    #pragma unroll
    for (int i = 0; i < 4; ++i) {
        __builtin_amdgcn_global_load_lds(
            (const __attribute__((address_space(1))) void*)(cnbc + srcb[i]),
            (__attribute__((address_space(3))) void*)((char*)&Bst[0][0][0] + ldso[i]),
            16, 0, 0);
    }
    __syncthreads();   // sinv visible

    // --- A: coalesced fp32 read -> normalize -> bf16 pack -> padded LDS
    #pragma unroll
    for (int it = 0; it < 8; ++it) {
        const int i = tid + it * 512;          // 4096 granules of 8 floats
        const int row = i >> 5, g = i & 31;
        const float* src = dv + (size_t)(r0 + row) * ND + g * 8;
        const float4 x = *(const float4*)src;
        const float4 y = *(const float4*)(src + 4);
        const float sc = sinv[row];
        uint4 pk;
        pk.x = (unsigned)f2bf(x.x * sc) | ((unsigned)f2bf(x.y * sc) << 16);
        pk.y = (unsigned)f2bf(x.z * sc) | ((unsigned)f2bf(x.w * sc) << 16);
        pk.z = (unsigned)f2bf(y.x * sc) | ((unsigned)f2bf(y.y * sc) << 16);
        pk.w = (unsigned)f2bf(y.z * sc) | ((unsigned)f2bf(y.w * sc) << 16);
        *(uint4*)&Al[row][g * 8] = pk;
    }
    __syncthreads();

    // --- A fragments -> registers, then PIN (opaque to regalloc/sinking)
    bf16x8 afr[4][8];
    #pragma unroll
    for (int mt = 0; mt < 4; ++mt)
        #pragma unroll
        for (int kt = 0; kt < 8; ++kt)
            afr[mt][kt] = *(const bf16x8*)&Al[mg * 64 + mt * 16 + lr][kt * 32 + lg * 8];
    #pragma unroll
    for (int mt = 0; mt < 4; ++mt)
        #pragma unroll
        for (int kt = 0; kt < 8; ++kt)
            asm volatile("" : "+v"(afr[mt][kt]));

    float se[4][4], sm[4][4];
    #pragma unroll
    for (int mt = 0; mt < 4; ++mt)
        #pragma unroll
        for (int r = 0; r < 4; ++r) { se[mt][r] = 0.f; sm[mt][r] = 0.f; }

    int town[4];
    #pragma unroll
    for (int mt = 0; mt < 4; ++mt) town[mt] = (r0 + mg * 64 + mt * 16) >> 5;

    for (int j = 0; j < 16; ++j) {
        __syncthreads();   // stage j landed; everyone done with buf j^1

        if (j < 15) {      // issue stage j+1 (in flight under compute)
            char* bdst = (char*)&Bst[(j + 1) & 1][0][0];
            const size_t soff = (size_t)(j + 1) * 32768;
            #pragma unroll
            for (int i = 0; i < 4; ++i) {
                __builtin_amdgcn_global_load_lds(
                    (const __attribute__((address_space(1))) void*)(cnbc + soff + srcb[i]),
                    (__attribute__((address_space(3))) void*)(bdst + ldso[i]),
                    16, 0, 0);
            }
        }

        const unsigned short (*bc)[256] = Bst[j & 1];
        f32x4 acc[4];
        #pragma unroll
        for (int mt = 0; mt < 4; ++mt) acc[mt] = (f32x4){0.f, 0.f, 0.f, 0.f};

        #pragma unroll
        for (int kt = 0; kt < 8; ++kt) {
            const bf16x8 bfr = *(const bf16x8*)&bc[ng * 16 + lr][((kt * 4 + lg) ^ rsw) * 8];
            #pragma unroll
            for (int mt = 0; mt < 4; ++mt)
                acc[mt] = __builtin_amdgcn_mfma_f32_16x16x32_bf16(afr[mt][kt], bfr, acc[mt], 0, 0, 0);
        }

        // branchless fixed-reference fold (cos <= 1 => reference max = 1)
        #pragma unroll
        for (int mt = 0; mt < 4; ++mt)
            #pragma unroll
            for (int r = 0; r < 4; ++r) {
                const float cv = acc[mt][r];
                se[mt][r] += EXP2F(fmaf(c2, cv, -c2));
                sm[mt][r] += cv;
            }

        // own-speaker column subtract (wave-uniform j/ng tests, lane lr test)
        #pragma unroll
        for (int mt = 0; mt < 4; ++mt) {
            const int tn = town[mt];
            if ((tn >> 6) == j && ((tn >> 4) & 3) == ng) {
                if (lr == (tn & 15)) {
                    #pragma unroll
                    for (int r = 0; r < 4; ++r) {
                        const float cv = acc[mt][r];
                        se[mt][r] -= EXP2F(fmaf(c2, cv, -c2));
                        sm[mt][r] -= cv;
                    }
                }
            }
        }
    }

    // reduce across the 16 column-lanes (xor bits 0..3)
    #pragma unroll
    for (int mask = 1; mask <= 8; mask <<= 1)
        #pragma unroll
        for (int mt = 0; mt < 4; ++mt)
            #pragma unroll
            for (int r = 0; r < 4; ++r) {
                se[mt][r] += __shfl_xor(se[mt][r], mask, 64);
                sm[mt][r] += __shfl_xor(sm[mt][r], mask, 64);
            }

    if (lr == 0) {
        #pragma unroll
        for (int mt = 0; mt < 4; ++mt)
            #pragma unroll
            for (int r = 0; r < 4; ++r) {
                const int row = mg * 64 + mt * 16 + lg * 4 + r;
                pse[ng][row] = se[mt][r];
                psm[ng][row] = sm[mt][r];
            }
    }
    __syncthreads();

    if (tid < BM) {
        const float st = pse[0][tid] + pse[1][tid] + pse[2][tid] + pse[3][tid];
        float smt = psm[0][tid] + psm[1][tid] + psm[2][tid] + psm[3][tid];
        float lse = w0 + b0 + __logf(st);
        #pragma unroll
        for (int mask = 1; mask <= 32; mask <<= 1) {
            lse += __shfl_xor(lse, mask, 64);
            smt += __shfl_xor(smt, mask, 64);
        }
        if ((tid & 63) == 0) { redn[tid >> 6] = smt; redl[tid >> 6] = lse; }
    }
    __syncthreads();
    if (tid == 0) {
        blk_neg[blk] = redn[0] + redn[1];
        blk_lse[blk] = redl[0] + redl[1];
    }
}

// ---------------------------------------------------------------------------
// Kernel 3: final reduction -> (loss, pos_mean, neg_mean)
// ---------------------------------------------------------------------------
__global__ __launch_bounds__(256) void ge2e_k3(
    const float* __restrict__ blk_pos, const float* __restrict__ blk_neg,
    const float* __restrict__ blk_lse, const float* __restrict__ wp,
    const float* __restrict__ bp, float* __restrict__ out)
{
    const int tid = threadIdx.x;
    __shared__ float red[12];
    float p = 0.f, n = 0.f, l = 0.f;
    for (int i = tid; i < NS; i += 256) p += blk_pos[i];
    if (tid < NBLK) { n = blk_neg[tid]; l = blk_lse[tid]; }
    #pragma unroll
    for (int off = 32; off > 0; off >>= 1) {
        p += __shfl_xor(p, off, 64);
        n += __shfl_xor(n, off, 64);
        l += __shfl_xor(l, off, 64);
    }
    const int wave = tid >> 6, lane = tid & 63;
    if (lane == 0) { red[wave] = p; red[4 + wave] = n; red[8 + wave] = l; }
    __syncthreads();
    if (tid == 0) {
        const float ps = red[0] + red[1] + red[2] + red[3];
        const float ns = red[4] + red[5] + red[6] + red[7];
        const float ls = red[8] + red[9] + red[10] + red[11];
        const float pos_mean = ps * (1.0f / NROWS);
        const float neg_mean = ns / ((float)NS * (float)NU * (float)(NS - 1));
        const float lse_mean = ls * (1.0f / NROWS);
        const float loss = -(wp[0] * pos_mean + bp[0]) + lse_mean;
        out[0] = loss;
        out[1] = pos_mean;
        out[2] = neg_mean;
    }
}

extern "C" void kernel_launch(void* const* d_in, const int* in_sizes, int n_in,
                              void* d_out, int out_size, void* d_ws, size_t ws_size,
                              hipStream_t stream)
{
    const float* dv = (const float*)d_in[0];
    const float* w  = (const float*)d_in[1];
    const float* b  = (const float*)d_in[2];
    float* out = (float*)d_out;

    unsigned short* cnb = (unsigned short*)d_ws;           // [NS][ND] bf16, 512 KB
    float* invn    = (float*)(cnb + (size_t)NS * ND);      // [NROWS]
    float* blk_pos = invn + NROWS;                         // [NS]
    float* blk_neg = blk_pos + NS;                         // [NBLK]
    float* blk_lse = blk_neg + NBLK;                       // [NBLK]

    hipLaunchKernelGGL(ge2e_k1, dim3(NS), dim3(256), 0, stream,
                       dv, cnb, invn, blk_pos);
    hipLaunchKernelGGL(ge2e_k2, dim3(NBLK), dim3(512), 0, stream,
                       dv, cnb, invn, w, b, blk_neg, blk_lse);
    hipLaunchKernelGGL(ge2e_k3, dim3(1), dim3(256), 0, stream,
                       blk_pos, blk_neg, blk_lse, w, b, out);
}